// Round 9
// baseline (19794.714 us; speedup 1.0000x reference)
//
#include <hip/hip_runtime.h>
#include <math.h>

#define SEQ   512
#define BATCH 128
#define INP   512
#define HID   1024
#define G4    4096   // 4*HID
#define NOUT  4

typedef short bf16x8 __attribute__((ext_vector_type(8)));
typedef float f32x4  __attribute__((ext_vector_type(4)));

__device__ __forceinline__ unsigned short f2bf(float x) {  // RNE fp32->bf16
  unsigned int u = __float_as_uint(x);
  unsigned int r = (u + 0x7FFFu + ((u >> 16) & 1u)) >> 16;
  return (unsigned short)r;
}
__device__ __forceinline__ float bf2f(unsigned short h) {
  return __uint_as_float(((unsigned int)h) << 16);
}

// uncached (system-scope, sc0+sc1) 16B load as 2x u64: bypasses L1+L2 so
// remote-XCD h writes are visible WITHOUT any cache-maintenance fences.
__device__ __forceinline__ bf16x8 ld_h16_uc(const unsigned short* p) {
  union { unsigned long long q[2]; bf16x8 v; } u;
  unsigned long long* pp = (unsigned long long*)(void*)p;
  u.q[0] = __hip_atomic_load(pp,     __ATOMIC_RELAXED, __HIP_MEMORY_SCOPE_SYSTEM);
  u.q[1] = __hip_atomic_load(pp + 1, __ATOMIC_RELAXED, __HIP_MEMORY_SCOPE_SYSTEM);
  return u.v;
}

// ---------------------------------------------------------------------------
// prepack W_hh [4096][1024] fp32 into fragment-linear bf16 hi/lo (proven):
// out index ((slab*32 + kstep)*64 + L)*8 + i  holds W[row][k] with
//   m=L&15, q=L>>4, row=(m&3)*HID + slab*4 + (m>>2), k=kstep*32+q*8+i.
// One slab = one 16-row M-tile (4 j's x 4 gates) = 32 KB per buffer.
// ---------------------------------------------------------------------------
__global__ void prepack_w(const float* __restrict__ W,
                          unsigned short* __restrict__ Whi,
                          unsigned short* __restrict__ Wlo) {
  int T = blockIdx.x * blockDim.x + threadIdx.x;   // < 256*32*64
  int L = T & 63;
  int kstep = (T >> 6) & 31;
  int bk = T >> 11;
  int m = L & 15, q = L >> 4;
  int row = (m & 3) * HID + bk * 4 + (m >> 2);
  int k = kstep * 32 + q * 8;
  const float* src = W + (size_t)row * HID + k;
  size_t o = (size_t)T * 8;
#pragma unroll
  for (int i = 0; i < 8; i++) {
    float x = src[i];
    unsigned short h = f2bf(x);
    Whi[o + i] = h;
    Wlo[o + i] = f2bf(x - bf2f(h));
  }
}

// ---------------------------------------------------------------------------
// init: h0 -> h_hi/h_lo bf16; c0 -> cT [H][B]; zero flag array (2048 uints).
// ---------------------------------------------------------------------------
__global__ void init_state(const float* __restrict__ h0, const float* __restrict__ c0,
                           unsigned short* __restrict__ hhi, unsigned short* __restrict__ hlo,
                           float* __restrict__ cT, unsigned int* __restrict__ flags) {
  int idx = blockIdx.x * blockDim.x + threadIdx.x;  // < BATCH*HID
  if (idx < 2048) flags[idx] = 0u;
  int b = idx >> 10;
  int j = idx & (HID - 1);
  float x = h0[idx];
  unsigned short h = f2bf(x);
  hhi[idx] = h;
  hlo[idx] = f2bf(x - bf2f(h));
  cT[j * BATCH + b] = c0[idx];
}

// ---------------------------------------------------------------------------
// transpose a chunk of inputs: in [nrows][INP] -> xt [INP][nrows]  (proven)
// ---------------------------------------------------------------------------
__global__ void transpose_in(const float* __restrict__ in, float* __restrict__ xt,
                             int nrows) {
  __shared__ float s[32][33];
  int tx = threadIdx.x & 31, ty = threadIdx.x >> 5;  // ty < 8
  int n0 = blockIdx.x * 32, i0 = blockIdx.y * 32;
#pragma unroll
  for (int r = 0; r < 4; r++) {
    int n = n0 + ty + 8 * r;
    s[ty + 8 * r][tx] = in[(size_t)n * INP + i0 + tx];
  }
  __syncthreads();
#pragma unroll
  for (int r = 0; r < 4; r++) {
    int i = i0 + ty + 8 * r;
    xt[(size_t)i * nrows + n0 + tx] = s[tx][ty + 8 * r];
  }
}

// ---------------------------------------------------------------------------
// gemm_xproj: C[4096][N] = W_ih[4096][512] @ Xt[512][N] + (b_ih + b_hh)
// PROVEN fp32 VALU kernel (~80% of fp32 vector peak; xp must stay exact
// fp32 — R13 showed bf16 xp error is amplified by the 512-step recurrence).
// ---------------------------------------------------------------------------
__global__ __launch_bounds__(256, 3)
void gemm_xproj(const float* __restrict__ A, const float* __restrict__ Bm,
                const float* __restrict__ b_ih, const float* __restrict__ b_hh,
                float* __restrict__ C, int N) {
  __shared__ float As[32][128];
  __shared__ float Bs[32][128];
  int t = threadIdx.x;
  int g0 = blockIdx.x * 128;
  int n0 = blockIdx.y * 128;
  int mg = (t >> 4) * 8, nn = (t & 15) * 8;
  float acc[8][8] = {};
  for (int k0 = 0; k0 < INP; k0 += 32) {
#pragma unroll
    for (int r = 0; r < 4; r++) {
      int idx = t + 256 * r;
      int g = idx >> 3, i4 = idx & 7;
      float4 v = *(const float4*)&A[(size_t)(g0 + g) * INP + k0 + 4 * i4];
      As[4 * i4 + 0][g] = v.x; As[4 * i4 + 1][g] = v.y;
      As[4 * i4 + 2][g] = v.z; As[4 * i4 + 3][g] = v.w;
    }
#pragma unroll
    for (int r = 0; r < 4; r++) {
      int idx = t + 256 * r;
      int kk = idx >> 5, n4 = idx & 31;
      *(float4*)&Bs[kk][4 * n4] = *(const float4*)&Bm[(size_t)(k0 + kk) * N + n0 + 4 * n4];
    }
    __syncthreads();
#pragma unroll 4
    for (int kk = 0; kk < 32; kk++) {
      float4 a0 = *(const float4*)&As[kk][mg];
      float4 a1 = *(const float4*)&As[kk][mg + 4];
      float4 bb0 = *(const float4*)&Bs[kk][nn];
      float4 bb1 = *(const float4*)&Bs[kk][nn + 4];
      float av[8] = {a0.x, a0.y, a0.z, a0.w, a1.x, a1.y, a1.z, a1.w};
      float bv[8] = {bb0.x, bb0.y, bb0.z, bb0.w, bb1.x, bb1.y, bb1.z, bb1.w};
#pragma unroll
      for (int i2 = 0; i2 < 8; i2++)
#pragma unroll
        for (int j2 = 0; j2 < 8; j2++)
          acc[i2][j2] = fmaf(av[i2], bv[j2], acc[i2][j2]);
    }
    __syncthreads();
  }
#pragma unroll
  for (int i2 = 0; i2 < 8; i2++) {
    int g = g0 + mg + i2;
    float bias = b_ih[g] + b_hh[g];
#pragma unroll
    for (int j2 = 0; j2 < 8; j2++) {
      C[(size_t)g * N + n0 + nn + j2] = acc[i2][j2] + bias;
    }
  }
}

// ---------------------------------------------------------------------------
// lstm_seq (R16): 2-BLOCKS-PER-CU retiling of the proven R15 kernel.
//
// R15 post-mortem: 18.6 us/step with MfmaUtil 7.3%, h-stream at 3.4 TB/s
// avg (far under L3 peak) -> the h-load phase is LATENCY-bound, and 128 KB
// LDS forced 1 wave/SIMD (zero TLP). Fix via TLP, not ILP (the R13/R14
// software pipeline broke correctness and is quarantined):
//   * block tile halved: ONE prepack slab (4 j's x 4 gates, 64 KB hi+lo
//     LDS) x 64 batches; acc0 only; 96 MFMAs/step/block.
//   * grid 512 blocks = 2 blocks/CU = 2 waves/SIMD: hardware interleaves
//     the two blocks' stalls — per-CU MFMA work unchanged, latency halves.
//   * barrier: same master-aggregated protocol; 512 flags (master lane
//     sweeps 2), go replicated x16 at flags[768+].
// Numerics bit-identical to R15 (same 3 MFMA terms, same order, same
// store path). Cooperative launch, checked fallback to plain launch (no
// grid.sync used; 512 blocks exactly co-resident by LDS capacity).
// ---------------------------------------------------------------------------
__global__ __launch_bounds__(256)
void lstm_seq(const unsigned short* __restrict__ Whi,
              const unsigned short* __restrict__ Wlo,
              const float* __restrict__ XP, int N, int CT, int step0,
              unsigned short* __restrict__ h0hi, unsigned short* __restrict__ h0lo,
              unsigned short* __restrict__ h1hi, unsigned short* __restrict__ h1lo,
              float* __restrict__ cT, unsigned int* flags) {
  __shared__ bf16x8 Wlds[4096];                 // 64 KB: [0..2047]=hi, [2048..]=lo
  __shared__ unsigned short hstage[64][2][12];  // 3 KB padded (R15-proven)

  int bk = blockIdx.x;            // 0..511
  int sblk = bk >> 1;             // slab 0..255 -> j0 = 4*sblk
  int bh2 = bk & 1;               // batch half
  int t = threadIdx.x;            // 0..255
  int w = t >> 6;                 // wave 0..3
  int L = t & 63;
  int n = L & 15, q = L >> 4;
  int b = bh2 * 64 + w * 16 + n;
  int j0 = sblk * 4 + q;

  // ---- stage ONE W slab (hi+lo, 64 KB) into LDS once per chunk ----
  {
    float4* ldsf = (float4*)Wlds;
    const float4* s1 = (const float4*)(Whi + (size_t)sblk * 16384);
    const float4* s2 = (const float4*)(Wlo + (size_t)sblk * 16384);
#pragma unroll
    for (int i = 0; i < 8; i++) ldsf[t + 256 * i] = s1[t + 256 * i];
#pragma unroll
    for (int i = 0; i < 8; i++) ldsf[2048 + t + 256 * i] = s2[t + 256 * i];
  }

  int ci0 = j0 * BATCH + b;
  float cc0 = cT[ci0];            // c in registers for the whole chunk

  size_t hoff = (size_t)b * HID + q * 8;

  // repack-store role (threads t<128): one u64 (4 shorts = this block's 4 j's)
  int r_bl  = t >> 1;             // 0..63 batch-local
  int r_arr = t & 1;              // 0=hi 1=lo
  size_t r_off = (size_t)(bh2 * 64 + r_bl) * HID + sblk * 4;  // 8B-aligned

  __syncthreads();

  // xp for tt=0 (cached loads; XP immutable during this kernel)
  float xa0[4];
#pragma unroll
  for (int g = 0; g < 4; g++)
    xa0[g] = XP[(size_t)(g * HID + j0) * N + b];

  for (int tt = 0; tt < CT; tt++) {
    int gs = step0 + tt;
    int odd = gs & 1;
    const unsigned short* Bh = (odd ? h1hi : h0hi) + hoff;
    const unsigned short* Bl = (odd ? h1lo : h0lo) + hoff;
    unsigned short* dhi = odd ? h0hi : h1hi;
    unsigned short* dlo = odd ? h0lo : h1lo;

    f32x4 acc0 = {0.f, 0.f, 0.f, 0.f};
#pragma unroll 8
    for (int ks = 0; ks < 32; ks++) {
      bf16x8 bhv = ld_h16_uc(Bh + ks * 32);
      bf16x8 blv = ld_h16_uc(Bl + ks * 32);
      bf16x8 ah0 = Wlds[ks * 64 + L];
      bf16x8 al0 = Wlds[2048 + ks * 64 + L];
      acc0 = __builtin_amdgcn_mfma_f32_16x16x32_bf16(ah0, bhv, acc0, 0, 0, 0);
      acc0 = __builtin_amdgcn_mfma_f32_16x16x32_bf16(ah0, blv, acc0, 0, 0, 0);
      acc0 = __builtin_amdgcn_mfma_f32_16x16x32_bf16(al0, bhv, acc0, 0, 0, 0);
    }

    {   // cell update (j = j0) -> LDS staging
      float i_ = 1.f / (1.f + expf(-(acc0[0] + xa0[0])));
      float f_ = 1.f / (1.f + expf(-(acc0[1] + xa0[1])));
      float g_ = tanhf(acc0[2] + xa0[2]);
      float o_ = 1.f / (1.f + expf(-(acc0[3] + xa0[3])));
      cc0 = f_ * cc0 + i_ * g_;
      float hn = o_ * tanhf(cc0);
      unsigned short hh = f2bf(hn);
      hstage[w * 16 + n][0][q] = hh;
      hstage[w * 16 + n][1][q] = f2bf(hn - bf2f(hh));
    }

    __syncthreads();   // hstage filled

    if (t < 128) {   // repack: one aligned u64 system-scope store/thread
      unsigned long long v =
          *(const unsigned long long*)&hstage[r_bl][r_arr][0];
      unsigned short* basep = r_arr ? dlo : dhi;
      __hip_atomic_store((unsigned long long*)(void*)(basep + r_off), v,
                         __ATOMIC_RELAXED, __HIP_MEMORY_SCOPE_SYSTEM);
    }

    // prefetch next step's xp (clamped index -> no UB); hides under barrier
    float xb0[4];
    {
      int tpf = (tt + 1 < CT) ? (tt + 1) : tt;
      const float* xpc = XP + (size_t)tpf * BATCH;
#pragma unroll
      for (int g = 0; g < 4; g++)
        xb0[g] = xpc[(size_t)(g * HID + j0) * N + b];
    }

    // ---- master-aggregated device barrier (no cache maintenance) ----
    unsigned tgt = (unsigned)(gs + 1);
    __syncthreads();   // vmcnt(0) in every wave: h stores globally visible
    if (t == 0)
      __hip_atomic_store(&flags[bk], tgt, __ATOMIC_RELAXED,
                         __HIP_MEMORY_SCOPE_SYSTEM);
    if (bk == 0) {
      unsigned gcnt = 0;   // each lane sweeps two blocks' flags
      while ((__hip_atomic_load(&flags[t], __ATOMIC_RELAXED,
                                __HIP_MEMORY_SCOPE_SYSTEM) < tgt ||
              __hip_atomic_load(&flags[t + 256], __ATOMIC_RELAXED,
                                __HIP_MEMORY_SCOPE_SYSTEM) < tgt) &&
             ++gcnt < (1u << 16))
        __builtin_amdgcn_s_sleep(1);
      __syncthreads();
      if (t < 16)   // replicate go across 16 lines (128 B apart)
        __hip_atomic_store(&flags[768 + t * 32], tgt, __ATOMIC_RELAXED,
                           __HIP_MEMORY_SCOPE_SYSTEM);
    } else if (t == 0) {
      unsigned gcnt = 0;
      const unsigned int* gop = &flags[768 + (bk & 15) * 32];
      while (__hip_atomic_load(gop, __ATOMIC_RELAXED,
                               __HIP_MEMORY_SCOPE_SYSTEM) < tgt &&
             ++gcnt < (1u << 16))
        __builtin_amdgcn_s_sleep(1);
    }
    __syncthreads();   // all waves held until go observed

#pragma unroll
    for (int g = 0; g < 4; g++) xa0[g] = xb0[g];
  }

  cT[ci0] = cc0;
}

// ---------------------------------------------------------------------------
// decode + softmax over batch dim (axis 0); h from hi+lo bf16 [B][H]
// ---------------------------------------------------------------------------
__global__ void decode_softmax(const unsigned short* __restrict__ hhi,
                               const unsigned short* __restrict__ hlo,
                               const float* __restrict__ Wd,
                               const float* __restrict__ bd, float* __restrict__ out) {
  __shared__ float lg[NOUT][BATCH];
  __shared__ float mx[NOUT], sm[NOUT];
  int t = threadIdx.x;  // 512 threads
  int b = t >> 2, o = t & 3;
  float s = bd[o];
  for (int j = 0; j < HID; j++) {
    float hv = bf2f(hhi[(size_t)b * HID + j]) + bf2f(hlo[(size_t)b * HID + j]);
    s += hv * Wd[o * HID + j];
  }
  lg[o][b] = s;
  __syncthreads();
  if (t < NOUT) {
    float m = -1e30f;
    for (int b2 = 0; b2 < BATCH; b2++) m = fmaxf(m, lg[t][b2]);
    float ss = 0.f;
    for (int b2 = 0; b2 < BATCH; b2++) ss += expf(lg[t][b2] - m);
    mx[t] = m; sm[t] = ss;
  }
  __syncthreads();
  out[b * NOUT + o] = expf(lg[o][b] - mx[o]) / sm[o];
}

// ---------------------------------------------------------------------------
extern "C" void kernel_launch(void* const* d_in, const int* in_sizes, int n_in,
                              void* d_out, int out_size, void* d_ws, size_t ws_size,
                              hipStream_t stream) {
  const float* inputs = (const float*)d_in[0];
  const float* h0     = (const float*)d_in[1];
  const float* c0     = (const float*)d_in[2];
  const float* W_ih   = (const float*)d_in[3];
  const float* W_hh   = (const float*)d_in[4];
  const float* b_ih   = (const float*)d_in[5];
  const float* b_hh   = (const float*)d_in[6];
  const float* W_dec  = (const float*)d_in[7];
  const float* b_dec  = (const float*)d_in[8];
  float* out = (float*)d_out;

  char* w = (char*)d_ws;
  unsigned short* Whi = (unsigned short*)w;  w += (size_t)G4 * HID * 2;
  unsigned short* Wlo = (unsigned short*)w;  w += (size_t)G4 * HID * 2;
  unsigned short* hhi[2], *hlo[2];
  hhi[0] = (unsigned short*)w;  w += (size_t)BATCH * HID * 2;
  hhi[1] = (unsigned short*)w;  w += (size_t)BATCH * HID * 2;
  hlo[0] = (unsigned short*)w;  w += (size_t)BATCH * HID * 2;
  hlo[1] = (unsigned short*)w;  w += (size_t)BATCH * HID * 2;
  float* cT = (float*)w;        w += (size_t)HID * BATCH * 4;
  unsigned int* flags = (unsigned int*)w;  w += 8192;   // 2048 uints
  size_t used = (size_t)(w - (char*)d_ws);

  // chunk size over timesteps, sized to fit ws (deterministic: ws_size const)
  size_t per_ct = ((size_t)INP * BATCH + (size_t)G4 * BATCH) * 4;  // Xt + XP per step
  int CT = 1;
  if (ws_size > used) {
    size_t avail = (ws_size - used) / per_ct;
    for (int c = SEQ; c >= 1; c >>= 1)
      if ((size_t)c <= avail) { CT = c; break; }
  }
  float* Xt = (float*)w;  w += (size_t)INP * BATCH * CT * 4;
  float* XP = (float*)w;
  int N = CT * BATCH;

  prepack_w<<<(256 * 32 * 64) / 256, 256, 0, stream>>>(W_hh, Whi, Wlo);
  init_state<<<BATCH * HID / 256, 256, 0, stream>>>(h0, c0, hhi[0], hlo[0], cT, flags);

  for (int t0 = 0; t0 < SEQ; t0 += CT) {
    transpose_in<<<dim3(N / 32, INP / 32), 256, 0, stream>>>(
        inputs + (size_t)t0 * BATCH * INP, Xt, N);
    gemm_xproj<<<dim3(G4 / 128, N / 128), 256, 0, stream>>>(
        W_ih, Xt, b_ih, b_hh, XP, N);

    int Nv = N, CTv = CT, step0 = t0;
    void* kargs[] = {
        (void*)&Whi, (void*)&Wlo, (void*)&XP, (void*)&Nv, (void*)&CTv,
        (void*)&step0, (void*)&hhi[0], (void*)&hlo[0], (void*)&hhi[1],
        (void*)&hlo[1], (void*)&cT, (void*)&flags};
    hipError_t ce = hipLaunchCooperativeKernel((const void*)lstm_seq, dim3(512),
                                               dim3(256), kargs, 0, stream);
    if (ce != hipSuccess) {   // no grid.sync inside; 512 blocks co-resident by LDS
      lstm_seq<<<512, 256, 0, stream>>>(Whi, Wlo, XP, Nv, CTv, step0,
                                        hhi[0], hlo[0], hhi[1], hlo[1], cT, flags);
    }
  }

  // SEQ even -> final h in buffer 0
  decode_softmax<<<1, 512, 0, stream>>>(hhi[0], hlo[0], W_dec, b_dec, out);
}